// Round 1
// baseline (135.013 us; speedup 1.0000x reference)
//
#include <hip/hip_runtime.h>
#include <cstddef>

#define Hdim 64
#define Wdim 64
#define Cdim 128
#define NH 4
#define DH 32
#define KW 7

// ---------------------------------------------------------------------------
// GEMM: C[M][N] = A[M][128] @ W[128][N] + bias[N]
// BM=128, BN=64, BK=64, 256 threads, per-thread 8 rows x 4 cols.
// A staged transposed in LDS (As[k][m], pad +4 keeps 16B alignment) so the
// inner loop is 3x ds_read_b128 per k-step for 32 FMAs.
// ---------------------------------------------------------------------------
__global__ __launch_bounds__(256) void gemm_bias_k128(
    const float* __restrict__ A, const float* __restrict__ W,
    const float* __restrict__ bias, float* __restrict__ C, int N)
{
    constexpr int K = 128, BM = 128, BN = 64, BK = 64;
    __shared__ float As[BK][BM + 4];
    __shared__ float Ws[BK][BN];

    const int m0 = blockIdx.x * BM;
    const int n0 = blockIdx.y * BN;
    const int tid = threadIdx.x;
    const int tx = tid & 15;   // 16 col groups * 4 cols = 64
    const int ty = tid >> 4;   // 16 row groups * 8 rows = 128

    float acc[8][4] = {};

    for (int kc = 0; kc < K; kc += BK) {
        // stage A tile (BM x BK = 8192 floats) transposed into As[k][m]
#pragma unroll
        for (int it = 0; it < (BM * BK) / (256 * 4); ++it) {
            int idx = (it * 256 + tid) * 4;
            int m = idx >> 6;      // / BK
            int k = idx & 63;      // % BK (multiple of 4)
            const float4 a = *(const float4*)(A + (size_t)(m0 + m) * K + kc + k);
            As[k + 0][m] = a.x;
            As[k + 1][m] = a.y;
            As[k + 2][m] = a.z;
            As[k + 3][m] = a.w;
        }
        // stage W tile (BK x BN = 4096 floats)
#pragma unroll
        for (int it = 0; it < (BK * BN) / (256 * 4); ++it) {
            int idx = (it * 256 + tid) * 4;
            int k = idx >> 6;      // / BN
            int n = idx & 63;      // % BN
            *(float4*)(&Ws[k][n]) = *(const float4*)(W + (size_t)(kc + k) * N + n0 + n);
        }
        __syncthreads();

#pragma unroll 8
        for (int k = 0; k < BK; ++k) {
            const float4 b4  = *(const float4*)(&Ws[k][tx * 4]);
            const float4 alo = *(const float4*)(&As[k][ty * 8]);
            const float4 ahi = *(const float4*)(&As[k][ty * 8 + 4]);
            const float a_[8] = {alo.x, alo.y, alo.z, alo.w, ahi.x, ahi.y, ahi.z, ahi.w};
            const float b_[4] = {b4.x, b4.y, b4.z, b4.w};
#pragma unroll
            for (int i = 0; i < 8; ++i)
#pragma unroll
                for (int j = 0; j < 4; ++j)
                    acc[i][j] = fmaf(a_[i], b_[j], acc[i][j]);
        }
        __syncthreads();
    }

    const float4 bia = *(const float4*)(bias + n0 + tx * 4);
#pragma unroll
    for (int i = 0; i < 8; ++i) {
        const size_t m = (size_t)(m0 + ty * 8 + i);
        float4 r;
        r.x = acc[i][0] + bia.x;
        r.y = acc[i][1] + bia.y;
        r.z = acc[i][2] + bia.z;
        r.w = acc[i][3] + bia.w;
        *(float4*)(C + m * N + n0 + tx * 4) = r;
    }
}

// ---------------------------------------------------------------------------
// Fused local attention. One block = (batch, head, 16x16 pixel tile).
// Stage 22x22 halo of K and V (32 floats each) into LDS with stride 36 floats
// (pad breaks the 32-float power-of-2 bank stride; 144B keeps b128 alignment).
// Each thread owns one pixel: q in regs, 49 scores in regs, softmax, PV.
// ---------------------------------------------------------------------------
#define TS 16
#define HALO (TS + KW - 1)   // 22
#define DPAD 36

__global__ __launch_bounds__(256) void local_attn_kernel(
    const float* __restrict__ qkv,   // [B*H*W][384]  (q | k | v)
    const float* __restrict__ rpb,   // [NH][13][13]
    float* __restrict__ outp)        // [B*H*W][128]
{
    __shared__ float kS[HALO * HALO * DPAD];
    __shared__ float vS[HALO * HALO * DPAD];
    __shared__ float rS[13 * 13];

    const int bh = blockIdx.x;          // b*NH + h
    const int b = bh >> 2;
    const int h = bh & 3;
    const int ty0 = blockIdx.y * TS;
    const int tx0 = blockIdx.z * TS;
    const int tid = threadIdx.x;

    // halo row/col range covered by this tile's windows
    const int lo_h = max(0, min(ty0 - 3, Hdim - KW));
    const int hi_h = min(max(ty0 + TS - 4, 0), Hdim - KW) + KW - 1;
    const int lo_w = max(0, min(tx0 - 3, Wdim - KW));
    const int hi_w = min(max(tx0 + TS - 4, 0), Wdim - KW) + KW - 1;
    const int ch = hi_h - lo_h + 1;
    const int cw = hi_w - lo_w + 1;
    const int npos = ch * cw;

    // stage K and V halo tiles (float4 per lane-iteration)
    for (int idx = tid; idx < npos * 8; idx += 256) {
        const int pos = idx >> 3;
        const int dq = idx & 7;
        const int ry = pos / cw;
        const int rx = pos - ry * cw;
        const int gy = lo_h + ry;
        const int gx = lo_w + rx;
        const size_t base = ((size_t)((b * Hdim + gy) * Wdim + gx)) * 384 + h * DH + dq * 4;
        const float4 kk = *(const float4*)(qkv + base + 128);
        const float4 vv = *(const float4*)(qkv + base + 256);
        *(float4*)(&kS[pos * DPAD + dq * 4]) = kk;
        *(float4*)(&vS[pos * DPAD + dq * 4]) = vv;
    }
    for (int i = tid; i < 13 * 13; i += 256) rS[i] = rpb[h * 169 + i];
    __syncthreads();

    const int py = tid >> 4, px = tid & 15;
    const int y = ty0 + py, x = tx0 + px;
    const int sh = max(0, min(y - 3, Hdim - KW));
    const int sw = max(0, min(x - 3, Wdim - KW));
    const size_t pix = (size_t)((b * Hdim + y) * Wdim + x);

    // q fragment (scaled)
    const float scale = 0.17677669529663687f;  // 32^-0.5
    float4 q[8];
#pragma unroll
    for (int i = 0; i < 8; ++i) {
        float4 t = *(const float4*)(qkv + pix * 384 + h * DH + i * 4);
        q[i].x = t.x * scale; q[i].y = t.y * scale;
        q[i].z = t.z * scale; q[i].w = t.w * scale;
    }

    const int bh0 = sh - y + 6;  // rpb row base
    const int bw0 = sw - x + 6;  // rpb col base

    float sc[49];
#pragma unroll
    for (int i = 0; i < KW; ++i) {
        const int ry = sh + i - lo_h;
#pragma unroll
        for (int j = 0; j < KW; ++j) {
            const int rx = sw + j - lo_w;
            const float* kp = &kS[(ry * cw + rx) * DPAD];
            float s0 = 0.f, s1 = 0.f, s2 = 0.f, s3 = 0.f;
#pragma unroll
            for (int d8 = 0; d8 < 8; ++d8) {
                const float4 k4 = *(const float4*)(kp + d8 * 4);
                s0 = fmaf(q[d8].x, k4.x, s0);
                s1 = fmaf(q[d8].y, k4.y, s1);
                s2 = fmaf(q[d8].z, k4.z, s2);
                s3 = fmaf(q[d8].w, k4.w, s3);
            }
            sc[i * KW + j] = (s0 + s1) + (s2 + s3) + rS[(bh0 + i) * 13 + (bw0 + j)];
        }
    }

    // softmax over 49
    float mx = sc[0];
#pragma unroll
    for (int t = 1; t < 49; ++t) mx = fmaxf(mx, sc[t]);
    float l = 0.f;
#pragma unroll
    for (int t = 0; t < 49; ++t) { sc[t] = __expf(sc[t] - mx); l += sc[t]; }
    const float inv = 1.f / l;

    // attn @ V
    float4 o[8] = {};
#pragma unroll
    for (int i = 0; i < KW; ++i) {
        const int ry = sh + i - lo_h;
#pragma unroll
        for (int j = 0; j < KW; ++j) {
            const int rx = sw + j - lo_w;
            const float w = sc[i * KW + j] * inv;
            const float* vp = &vS[(ry * cw + rx) * DPAD];
#pragma unroll
            for (int d8 = 0; d8 < 8; ++d8) {
                const float4 v4 = *(const float4*)(vp + d8 * 4);
                o[d8].x = fmaf(w, v4.x, o[d8].x);
                o[d8].y = fmaf(w, v4.y, o[d8].y);
                o[d8].z = fmaf(w, v4.z, o[d8].z);
                o[d8].w = fmaf(w, v4.w, o[d8].w);
            }
        }
    }
#pragma unroll
    for (int d8 = 0; d8 < 8; ++d8)
        *(float4*)(outp + pix * Cdim + h * DH + d8 * 4) = o[d8];
}

// ---------------------------------------------------------------------------
extern "C" void kernel_launch(void* const* d_in, const int* in_sizes, int n_in,
                              void* d_out, int out_size, void* d_ws, size_t ws_size,
                              hipStream_t stream) {
    const float* x      = (const float*)d_in[0];   // (4,64,64,128)
    const float* w_qkv  = (const float*)d_in[1];   // (128,384)
    const float* b_qkv  = (const float*)d_in[2];   // (384,)
    const float* rpb    = (const float*)d_in[3];   // (4,13,13)
    const float* w_proj = (const float*)d_in[4];   // (128,128)
    const float* b_proj = (const float*)d_in[5];   // (128,)
    float* out = (float*)d_out;

    const int M = 4 * Hdim * Wdim;                 // 16384
    float* qkv  = (float*)d_ws;                    // M x 384
    float* attn = qkv + (size_t)M * 384;           // M x 128

    dim3 blk(256);
    // qkv = x @ w_qkv + b_qkv
    gemm_bias_k128<<<dim3(M / 128, 384 / 64), blk, 0, stream>>>(x, w_qkv, b_qkv, qkv, 384);
    // local attention (fused scores + bias + softmax + PV)
    local_attn_kernel<<<dim3(4 * NH, Hdim / TS, Wdim / TS), blk, 0, stream>>>(qkv, rpb, attn);
    // out = attn @ w_proj + b_proj
    gemm_bias_k128<<<dim3(M / 128, 128 / 64), blk, 0, stream>>>(attn, w_proj, b_proj, out, 128);
}

// Round 2
// 125.188 us; speedup vs baseline: 1.0785x; 1.0785x over previous
//
#include <hip/hip_runtime.h>
#include <cstddef>
#include <cstdint>

#define Hdim 64
#define Wdim 64
#define NH 4
#define DH 32
#define KW 7

typedef _Float16 v2h __attribute__((ext_vector_type(2)));

#if defined(__has_builtin)
#if __has_builtin(__builtin_amdgcn_fdot2)
#define HAVE_FDOT2 1
#endif
#endif

__device__ __forceinline__ float fdot2acc(v2h a, v2h b, float c) {
#ifdef HAVE_FDOT2
    return __builtin_amdgcn_fdot2(a, b, c, false);
#else
    return fmaf((float)a.x, (float)b.x, fmaf((float)a.y, (float)b.y, c));
#endif
}

union F16x8 {
    uint4 u;
    v2h h[4];
};

// ---------------------------------------------------------------------------
// GEMM1: qkv = x @ w_qkv + b_qkv, output fp16 in [sel][b][h][yx][32] layout,
// q pre-scaled by 32^-0.5. BM=64, BN=128, BK=32, 256 thr, 4x8 acc.
// Grid: (16384/64, 3) = 768 blocks, ~25.6 KB LDS -> 6 blocks/CU cap, 3/CU real.
// ---------------------------------------------------------------------------
__global__ __launch_bounds__(256) void gemm_qkv(
    const float* __restrict__ A,      // x [16384][128]
    const float* __restrict__ W,      // w_qkv [128][384]
    const float* __restrict__ bias,   // [384]
    _Float16* __restrict__ qkvh)      // [3][16][4096][32]
{
    __shared__ float As[32][68];      // transposed [k][m]
    __shared__ float Ws[32][132];     // [k][n]

    const int m0 = blockIdx.x * 64;
    const int sel = blockIdx.y;       // 0=q,1=k,2=v
    const int n0 = sel * 128;
    const int tid = threadIdx.x;
    const int tx = tid & 15;          // 16 col groups * 8 cols
    const int ty = tid >> 4;          // 16 row groups * 4 rows

    float acc[4][8] = {};

    for (int kc = 0; kc < 128; kc += 32) {
        // stage A (64x32) transposed: 512 float4, 2 per thread
#pragma unroll
        for (int it = 0; it < 2; ++it) {
            int idx = it * 256 + tid;
            int m = idx >> 3;
            int k = (idx & 7) * 4;
            const float4 a = *(const float4*)(A + (size_t)(m0 + m) * 128 + kc + k);
            As[k + 0][m] = a.x; As[k + 1][m] = a.y;
            As[k + 2][m] = a.z; As[k + 3][m] = a.w;
        }
        // stage W (32x128): 1024 float4, 4 per thread
#pragma unroll
        for (int it = 0; it < 4; ++it) {
            int idx = it * 256 + tid;
            int k = idx >> 5;
            int n = (idx & 31) * 4;
            *(float4*)(&Ws[k][n]) = *(const float4*)(W + (size_t)(kc + k) * 384 + n0 + n);
        }
        __syncthreads();

#pragma unroll 8
        for (int k = 0; k < 32; ++k) {
            const float4 a4 = *(const float4*)(&As[k][ty * 4]);
            const float4 b0 = *(const float4*)(&Ws[k][tx * 8]);
            const float4 b1 = *(const float4*)(&Ws[k][tx * 8 + 4]);
            const float a_[4] = {a4.x, a4.y, a4.z, a4.w};
            const float b_[8] = {b0.x, b0.y, b0.z, b0.w, b1.x, b1.y, b1.z, b1.w};
#pragma unroll
            for (int i = 0; i < 4; ++i)
#pragma unroll
                for (int j = 0; j < 8; ++j)
                    acc[i][j] = fmaf(a_[i], b_[j], acc[i][j]);
        }
        __syncthreads();
    }

    const float qscale = (sel == 0) ? 0.17677669529663687f : 1.0f;
    const int h = tx >> 2;            // head
    const int d0 = (tx & 3) * 8;      // dim offset within head
    float bv[8];
#pragma unroll
    for (int j = 0; j < 8; ++j) bv[j] = bias[n0 + tx * 8 + j];

#pragma unroll
    for (int i = 0; i < 4; ++i) {
        const int m = m0 + ty * 4 + i;
        const int b = m >> 12;
        const int yx = m & 4095;
        _Float16 tmp[8];
#pragma unroll
        for (int j = 0; j < 8; ++j)
            tmp[j] = (_Float16)((acc[i][j] + bv[j]) * qscale);
        _Float16* dst = qkvh + ((size_t)sel * 16 + b * 4 + h) * 131072 + (size_t)yx * 32 + d0;
        *(uint4*)dst = *(const uint4*)tmp;
    }
}

// ---------------------------------------------------------------------------
// Fused local attention, quad-split: block = (b*4+h, 8x8 tile), 256 threads =
// 64 pixels x 4 dim-quarters. K/V halo (<=14x14) staged fp16 in LDS, stride
// 40 halves (80 B, 16B-aligned, breaks pow-2 bank stride). Scores via
// v_dot2_f32_f16 partials + 2 shuffles; softmax redundant per quad; PV per
// 8-dim quarter. LDS ~32 KB -> 4 blocks/CU; grid 1024 = 4/CU, 16 waves/CU.
// ---------------------------------------------------------------------------
#define ATS 8
#define AMAXPOS 196   // 14*14
#define KST 40        // halves per position

__global__ __launch_bounds__(256, 4) void local_attn(
    const _Float16* __restrict__ qkvh,  // [3][16][4096][32]
    const float* __restrict__ rpb,      // [4][13][13]
    float* __restrict__ outp)           // [16384][128]
{
    __shared__ _Float16 kS[AMAXPOS * KST];
    __shared__ _Float16 vS[AMAXPOS * KST];
    __shared__ float rS[169];

    const int bh = blockIdx.x;       // b*4 + h
    const int h = bh & 3;
    const int ty0 = blockIdx.y * ATS;
    const int tx0 = blockIdx.z * ATS;
    const int tid = threadIdx.x;

    const int lo_h = max(0, min(ty0 - 3, Hdim - KW));
    const int hi_h = min(ty0 + ATS - 4, Hdim - KW) + KW - 1;
    const int lo_w = max(0, min(tx0 - 3, Wdim - KW));
    const int hi_w = min(tx0 + ATS - 4, Wdim - KW) + KW - 1;
    const int ch = hi_h - lo_h + 1;
    const int cw = hi_w - lo_w + 1;
    const int npos = ch * cw;

    const _Float16* kbase = qkvh + (size_t)(16 + bh) * 131072;
    const _Float16* vbase = qkvh + (size_t)(32 + bh) * 131072;

    for (int idx = tid; idx < npos * 4; idx += 256) {
        const int pos = idx >> 2;
        const int c = idx & 3;
        const int ry = pos / cw;
        const int rx = pos - ry * cw;
        const size_t g = ((size_t)(lo_h + ry) * Wdim + (lo_w + rx)) * 32 + c * 8;
        *(uint4*)(kS + pos * KST + c * 8) = *(const uint4*)(kbase + g);
        *(uint4*)(vS + pos * KST + c * 8) = *(const uint4*)(vbase + g);
    }
    for (int i = tid; i < 169; i += 256) rS[i] = rpb[h * 169 + i];
    __syncthreads();

    const int p = tid >> 2;          // pixel 0..63
    const int q = tid & 3;           // dim quarter
    const int py = p >> 3, px = p & 7;
    const int y = ty0 + py, x = tx0 + px;
    const int sh = max(0, min(y - 3, Hdim - KW));
    const int sw = max(0, min(x - 3, Wdim - KW));
    const int rb = sh - lo_h;
    const int cb = sw - lo_w;
    const int bh0 = sh - y + 6;      // rpb row base (0..6)
    const int bw0 = sw - x + 6;

    // q fragment: 8 halves, pre-scaled
    F16x8 qf;
    qf.u = *(const uint4*)(qkvh + (size_t)bh * 131072 + ((size_t)y * Wdim + x) * 32 + q * 8);

    float sc[49];
#pragma unroll
    for (int i = 0; i < KW; ++i) {
        const _Float16* kp = kS + ((rb + i) * cw + cb) * KST + q * 8;
        const int bi = (bh0 + i) * 13 + bw0;
#pragma unroll
        for (int j = 0; j < KW; ++j) {
            F16x8 kf;
            kf.u = *(const uint4*)(kp + j * KST);
            float s = fdot2acc(qf.h[0], kf.h[0],
                      fdot2acc(qf.h[1], kf.h[1],
                      fdot2acc(qf.h[2], kf.h[2],
                      fdot2acc(qf.h[3], kf.h[3], 0.0f))));
            s += __shfl_xor(s, 1);
            s += __shfl_xor(s, 2);
            sc[i * KW + j] = s + rS[bi + j];
        }
    }

    float mx = sc[0];
#pragma unroll
    for (int t = 1; t < 49; ++t) mx = fmaxf(mx, sc[t]);
    float l = 0.f;
#pragma unroll
    for (int t = 0; t < 49; ++t) { sc[t] = __expf(sc[t] - mx); l += sc[t]; }
    const float inv = 1.f / l;

    float o[8] = {};
#pragma unroll
    for (int i = 0; i < KW; ++i) {
        const _Float16* vp = vS + ((rb + i) * cw + cb) * KST + q * 8;
#pragma unroll
        for (int j = 0; j < KW; ++j) {
            F16x8 vf;
            vf.u = *(const uint4*)(vp + j * KST);
            const float w = sc[i * KW + j] * inv;
#pragma unroll
            for (int d = 0; d < 4; ++d) {
                o[2 * d + 0] = fmaf(w, (float)vf.h[d].x, o[2 * d + 0]);
                o[2 * d + 1] = fmaf(w, (float)vf.h[d].y, o[2 * d + 1]);
            }
        }
    }

    const size_t pix = (size_t)(bh >> 2) * 4096 + (size_t)y * Wdim + x;
    float* dst = outp + pix * 128 + h * DH + q * 8;
    *(float4*)(dst)     = make_float4(o[0], o[1], o[2], o[3]);
    *(float4*)(dst + 4) = make_float4(o[4], o[5], o[6], o[7]);
}

// ---------------------------------------------------------------------------
// GEMM2: out = attn @ w_proj + b_proj. BM=64, BN=64, BK=32, 4x4 acc.
// Grid (256,2) = 512 blocks, ~17 KB LDS.
// ---------------------------------------------------------------------------
__global__ __launch_bounds__(256) void gemm_proj(
    const float* __restrict__ A,      // attn [16384][128]
    const float* __restrict__ W,      // w_proj [128][128]
    const float* __restrict__ bias,   // [128]
    float* __restrict__ C)            // out [16384][128]
{
    __shared__ float As[32][68];
    __shared__ float Ws[32][64];

    const int m0 = blockIdx.x * 64;
    const int n0 = blockIdx.y * 64;
    const int tid = threadIdx.x;
    const int tx = tid & 15;
    const int ty = tid >> 4;

    float acc[4][4] = {};

    for (int kc = 0; kc < 128; kc += 32) {
#pragma unroll
        for (int it = 0; it < 2; ++it) {
            int idx = it * 256 + tid;
            int m = idx >> 3;
            int k = (idx & 7) * 4;
            const float4 a = *(const float4*)(A + (size_t)(m0 + m) * 128 + kc + k);
            As[k + 0][m] = a.x; As[k + 1][m] = a.y;
            As[k + 2][m] = a.z; As[k + 3][m] = a.w;
        }
#pragma unroll
        for (int it = 0; it < 2; ++it) {
            int idx = it * 256 + tid;
            int k = idx >> 4;
            int n = (idx & 15) * 4;
            *(float4*)(&Ws[k][n]) = *(const float4*)(W + (size_t)(kc + k) * 128 + n0 + n);
        }
        __syncthreads();

#pragma unroll 8
        for (int k = 0; k < 32; ++k) {
            const float4 a4 = *(const float4*)(&As[k][ty * 4]);
            const float4 b4 = *(const float4*)(&Ws[k][tx * 4]);
            const float a_[4] = {a4.x, a4.y, a4.z, a4.w};
            const float b_[4] = {b4.x, b4.y, b4.z, b4.w};
#pragma unroll
            for (int i = 0; i < 4; ++i)
#pragma unroll
                for (int j = 0; j < 4; ++j)
                    acc[i][j] = fmaf(a_[i], b_[j], acc[i][j]);
        }
        __syncthreads();
    }

    const float4 bia = *(const float4*)(bias + n0 + tx * 4);
#pragma unroll
    for (int i = 0; i < 4; ++i) {
        const size_t m = (size_t)(m0 + ty * 4 + i);
        float4 r;
        r.x = acc[i][0] + bia.x;
        r.y = acc[i][1] + bia.y;
        r.z = acc[i][2] + bia.z;
        r.w = acc[i][3] + bia.w;
        *(float4*)(C + m * 128 + n0 + tx * 4) = r;
    }
}

// ---------------------------------------------------------------------------
extern "C" void kernel_launch(void* const* d_in, const int* in_sizes, int n_in,
                              void* d_out, int out_size, void* d_ws, size_t ws_size,
                              hipStream_t stream) {
    const float* x      = (const float*)d_in[0];
    const float* w_qkv  = (const float*)d_in[1];
    const float* b_qkv  = (const float*)d_in[2];
    const float* rpb    = (const float*)d_in[3];
    const float* w_proj = (const float*)d_in[4];
    const float* b_proj = (const float*)d_in[5];
    float* out = (float*)d_out;

    _Float16* qkvh = (_Float16*)d_ws;                         // 3*16*4096*32 halves
    float* attnb = (float*)((char*)d_ws + 3ULL * 16 * 4096 * 32 * 2);  // 16384*128 fp32

    dim3 blk(256);
    gemm_qkv<<<dim3(16384 / 64, 3), blk, 0, stream>>>(x, w_qkv, b_qkv, qkvh);
    local_attn<<<dim3(16, Hdim / ATS, Wdim / ATS), blk, 0, stream>>>(qkvh, rpb, attnb);
    gemm_proj<<<dim3(16384 / 64, 2), blk, 0, stream>>>(attnb, w_proj, b_proj, out);
}